// Round 17
// baseline (780.517 us; speedup 1.0000x reference)
//
#include <hip/hip_runtime.h>
#include <hip/hip_bf16.h>

#define EMB_D 100
#define HID 64
#define G4 256
#define BATCH 128
#define SEQ 1024
#define TOK 64
#define LOG2E 1.44269504f

typedef _Float16 half2v __attribute__((ext_vector_type(2)));
typedef unsigned short u16;
typedef unsigned int   u32;

__device__ __forceinline__ float rcpf(float x) { return __builtin_amdgcn_rcpf(x); }
__device__ __forceinline__ float ex2(float x) { return __builtin_amdgcn_exp2f(x); }
__device__ __forceinline__ float sig_pre(float xp) { return rcpf(1.0f + ex2(-xp)); }
__device__ __forceinline__ float tanh_pre(float xp) {
  float t = ex2(-2.0f * fabsf(xp));
  return copysignf((1.0f - t) * rcpf(1.0f + t), xp);
}
__device__ __forceinline__ float tanh_nat(float x) {
  float t = ex2(-2.885390082f * fabsf(x));
  return copysignf((1.0f - t) * rcpf(1.0f + t), x);
}
__device__ __forceinline__ float sig_nat(float x) { return rcpf(1.0f + ex2(-LOG2E * x)); }

__device__ __forceinline__ float dot2(u32 h, u32 w, float acc) {
  return __builtin_amdgcn_fdot2(__builtin_bit_cast(half2v, h),
                                __builtin_bit_cast(half2v, w), acc, false);
}
__device__ __forceinline__ u32 packh2(float lo, float hi) {
  u16 a = __builtin_bit_cast(u16, (_Float16)lo);
  u16 b = __builtin_bit_cast(u16, (_Float16)hi);
  return (u32)a | ((u32)b << 16);
}
// quad butterfly sum (4-lane groups): xor1 + xor2, 2-deep
template <int CTRL>
__device__ __forceinline__ float dppadd(float v) {
  int x = __builtin_amdgcn_mov_dpp(__builtin_bit_cast(int, v), CTRL, 0xF, 0xF, true);
  return v + __builtin_bit_cast(float, x);
}
#define QREDUCE(v) do { v = dppadd<0xB1>(v); v = dppadd<0x4E>(v); } while (0)

// 8 dot2 over one K-quarter (2 uint4 of h, 2 uint4 of w)
__device__ __forceinline__ float q8(uint4 ha, uint4 hb, uint4 wa, uint4 wb) {
  float a0 = dot2(ha.x, wa.x, 0.f);
  float a1 = dot2(ha.y, wa.y, 0.f);
  float a2 = dot2(ha.z, wa.z, 0.f);
  float a3 = dot2(ha.w, wa.w, 0.f);
  a0 = dot2(hb.x, wb.x, a0);
  a1 = dot2(hb.y, wb.y, a1);
  a2 = dot2(hb.z, wb.z, a2);
  a3 = dot2(hb.w, wb.w, a3);
  return (a0 + a1) + (a2 + a3);
}

// --- prep: biases (pre-scaled, quartet-packed) + packed weights (x LOG2E) ---
__global__ void prep_kernel(const float* __restrict__ Wih0,
                            const float* __restrict__ Whh0, const float* __restrict__ Wih1,
                            const float* __restrict__ Whh1,
                            const float* __restrict__ bih0, const float* __restrict__ bhh0,
                            const float* __restrict__ bih1, const float* __restrict__ bhh1,
                            u32* __restrict__ Wih0T2, float* __restrict__ b0c,
                            float4* __restrict__ b1q,
                            u32* __restrict__ Whh0h, u32* __restrict__ Wih1h,
                            u32* __restrict__ Whh1h) {
  int g = threadIdx.x;
  b0c[g] = (bih0[g] + bhh0[g]) * LOG2E;
  if (g < HID) {
    b1q[g] = make_float4((bih1[g] + bhh1[g]) * LOG2E,
                         (bih1[g + 64] + bhh1[g + 64]) * LOG2E,
                         (bih1[g + 128] + bhh1[g + 128]) * LOG2E,
                         (bih1[g + 192] + bhh1[g + 192]) * LOG2E);
  }
  for (int dp = 0; dp < 50; ++dp)
    Wih0T2[dp * G4 + g] = packh2(Wih0[g * EMB_D + 2 * dp] * LOG2E,
                                 Wih0[g * EMB_D + 2 * dp + 1] * LOG2E);
  for (int d = 0; d < 32; ++d) {
    Whh0h[g * 32 + d] = packh2(Whh0[g * HID + 2 * d] * LOG2E, Whh0[g * HID + 2 * d + 1] * LOG2E);
    Wih1h[g * 32 + d] = packh2(Wih1[g * HID + 2 * d] * LOG2E, Wih1[g * HID + 2 * d + 1] * LOG2E);
    Whh1h[g * 32 + d] = packh2(Whh1[g * HID + 2 * d] * LOG2E, Whh1[g * HID + 2 * d + 1] * LOG2E);
  }
}

// --- xw0: f16 dot2 GEMV; output layout [t][e*4 + gate] (quartet-contiguous) ---
__global__ __attribute__((amdgpu_waves_per_eu(1, 4))) __launch_bounds__(256)
void xw0_kernel(
    const int* __restrict__ x, const float* __restrict__ emb,
    const u32* __restrict__ Wih0T2, const float* __restrict__ b0c,
    u16* __restrict__ xwP) {
  __shared__ int sidx[TOK];
  __shared__ alignas(16) u32 erow[TOK][52];
  int g = threadIdx.x;
  long t0 = (long)blockIdx.x * TOK;

  if (g < TOK) sidx[g] = x[t0 + g];
  __syncthreads();
  for (int i = g; i < TOK * 50; i += 256) {
    int tok = i / 50, dp = i - tok * 50;
    const float* er = emb + (size_t)sidx[tok] * EMB_D + 2 * dp;
    erow[tok][dp] = packh2(er[0], er[1]);
  }
  for (int i = g; i < TOK * 2; i += 256) erow[i >> 1][50 + (i & 1)] = 0;

  u32 wreg[52];
  #pragma unroll
  for (int dp = 0; dp < 50; ++dp) wreg[dp] = Wih0T2[dp * G4 + g];
  wreg[50] = 0; wreg[51] = 0;
  float bb = b0c[g];
  __syncthreads();

  const int e = g & 63, q = g >> 6;
  for (int tok = 0; tok < TOK; ++tok) {
    const uint4* ep = (const uint4*)erow[tok];
    float a0 = bb, a1 = 0.f, a2 = 0.f, a3 = 0.f;
    #pragma unroll
    for (int c = 0; c < 13; ++c) {
      uint4 hv = ep[c];
      a0 = dot2(hv.x, wreg[4 * c],     a0);
      a1 = dot2(hv.y, wreg[4 * c + 1], a1);
      a2 = dot2(hv.z, wreg[4 * c + 2], a2);
      a3 = dot2(hv.w, wreg[4 * c + 3], a3);
    }
    xwP[((size_t)(t0 + tok)) * G4 + e * 4 + q] =
        __builtin_bit_cast(u16, (_Float16)((a0 + a1) + (a2 + a3)));
  }
}

// --- fused recurrence: merged layers + K-quarter split + quad reduce ---
// 128 blocks x 256 threads (4 waves, 1/SIMD). Lane (e = w*16+(l>>2), k = l&3)
// reads ONLY K-quarter k of h0/h1 (4 ds_read_b128/wave/step vs 16 -> DS pipe
// 16 instr/CU vs 64), computes all 4 gate partials over that quarter (96 dot2,
// weights sliced by quarter: same 24 uint4), quad-butterfly (xor1+xor2 DPP)
// sums the quartet -> every lane holds full (i,f,g,o); act lane-local; k==0
// writes h. One barrier/step.
__global__ __attribute__((amdgpu_waves_per_eu(1, 1))) __launch_bounds__(256)
void lstm_fused_kernel(
    const u16* __restrict__ xwP,
    const u32* __restrict__ Whh0h, const u32* __restrict__ Wih1h,
    const u32* __restrict__ Whh1h, const float4* __restrict__ b1q,
    const float* __restrict__ W1, const float* __restrict__ clsb1,
    const float* __restrict__ W2, const float* __restrict__ clsb2,
    float* __restrict__ out) {
  int tid = threadIdx.x;
  int l = tid & 63;
  int w = tid >> 6;
  int e = w * 16 + (l >> 2);
  int k = l & 3;
  int b = blockIdx.x;

  __shared__ alignas(16) _Float16 h0s[2][HID];
  __shared__ alignas(16) _Float16 h1s[2][HID];
  __shared__ alignas(16) float hf[HID];

  // weights: gate g, row g*64+e, K-quarter k -> 2 uint4 at uint4-idx row*8+2k
  uint4 w0[8], w1[8], w2[8];
  #pragma unroll
  for (int g = 0; g < 4; ++g) {
    int row = g * HID + e;
    const uint4* p0 = (const uint4*)(Whh0h + row * 32 + 8 * k);
    const uint4* p1 = (const uint4*)(Wih1h + row * 32 + 8 * k);
    const uint4* p2 = (const uint4*)(Whh1h + row * 32 + 8 * k);
    w0[2 * g] = p0[0]; w0[2 * g + 1] = p0[1];
    w1[2 * g] = p1[0]; w1[2 * g + 1] = p1[1];
    w2[2 * g] = p2[0]; w2[2 * g + 1] = p2[1];
  }
  #pragma unroll
  for (int c = 0; c < 8; ++c) {
    asm volatile("" : "+v"(w0[c].x), "+v"(w0[c].y), "+v"(w0[c].z), "+v"(w0[c].w));
    asm volatile("" : "+v"(w1[c].x), "+v"(w1[c].y), "+v"(w1[c].z), "+v"(w1[c].w));
    asm volatile("" : "+v"(w2[c].x), "+v"(w2[c].y), "+v"(w2[c].z), "+v"(w2[c].w));
  }
  float4 bq = b1q[e];

  if (tid < 128) ((u16*)h0s)[tid] = 0;
  else           ((u16*)h1s)[tid - 128] = 0;

  const u16* xb = xwP + (size_t)b * SEQ * G4 + e * 4;
  uint2 xwA = *(const uint2*)(xb);
  uint2 xwB = *(const uint2*)(xb + G4);
  float c0 = 0.f, c1 = 0.f;
  __syncthreads();

  for (int t = 0; t <= SEQ; ++t) {
    int rb = (t + 1) & 1, wb = t & 1;
    // lane's K-quarter of h0,h1: 2 uint4 each at uint4-idx 2k
    uint4 h0a, h0b, h1a, h1b;
    {
      const uint4* p0 = (const uint4*)h0s[rb];
      const uint4* p1 = (const uint4*)h1s[rb];
      h0a = p0[2 * k]; h0b = p0[2 * k + 1];
      h1a = p1[2 * k]; h1b = p1[2 * k + 1];
    }
    int tn = (t + 2 < SEQ) ? (t + 2) : (SEQ - 1);
    uint2 xwC = *(const uint2*)(xb + (size_t)tn * G4);

    // L0: h0_t (skip at t==SEQ)
    if (t < SEQ) {
      float p0 = q8(h0a, h0b, w0[0], w0[1]);
      float p1 = q8(h0a, h0b, w0[2], w0[3]);
      float p2 = q8(h0a, h0b, w0[4], w0[5]);
      float p3 = q8(h0a, h0b, w0[6], w0[7]);
      QREDUCE(p0); QREDUCE(p1); QREDUCE(p2); QREDUCE(p3);
      half2v xif = __builtin_bit_cast(half2v, xwA.x);
      half2v xgo = __builtin_bit_cast(half2v, xwA.y);
      float gi = p0 + (float)xif[0];
      float gf = p1 + (float)xif[1];
      float gg = p2 + (float)xgo[0];
      float go = p3 + (float)xgo[1];
      c0 = sig_pre(gf) * c0 + sig_pre(gi) * tanh_pre(gg);
      float hv0 = sig_pre(go) * tanh_nat(c0);
      if (k == 0) h0s[wb][e] = (_Float16)hv0;
    }

    // L1: h1_{t-1} from h0_{t-1}, h1_{t-2} (active t>=1)
    if (t >= 1) {
      float p0 = q8(h0a, h0b, w1[0], w1[1]) + q8(h1a, h1b, w2[0], w2[1]);
      float p1 = q8(h0a, h0b, w1[2], w1[3]) + q8(h1a, h1b, w2[2], w2[3]);
      float p2 = q8(h0a, h0b, w1[4], w1[5]) + q8(h1a, h1b, w2[4], w2[5]);
      float p3 = q8(h0a, h0b, w1[6], w1[7]) + q8(h1a, h1b, w2[6], w2[7]);
      QREDUCE(p0); QREDUCE(p1); QREDUCE(p2); QREDUCE(p3);
      float gi = p0 + bq.x;
      float gf = p1 + bq.y;
      float gg = p2 + bq.z;
      float go = p3 + bq.w;
      c1 = sig_pre(gf) * c1 + sig_pre(gi) * tanh_pre(gg);
      float hv1 = sig_pre(go) * tanh_nat(c1);
      if (k == 0) {
        h1s[wb][e] = (_Float16)hv1;
        if (t == SEQ) hf[e] = hv1;
      }
    }

    xwA = xwB; xwB = xwC;
    asm volatile("s_waitcnt lgkmcnt(0)" ::: "memory");
    __builtin_amdgcn_s_barrier();
    asm volatile("" ::: "memory");
  }
  __syncthreads();

  // classifier (wave 0): z = relu(h1.W1^T + b1); out = sigmoid(z.W2 + b2)
  if (w == 0) {
    int j = l;
    const float4* wp = (const float4*)(W1 + j * HID);
    const float4* hp = (const float4*)hf;
    float z0 = clsb1[j], z1 = 0.f, z2 = 0.f, z3 = 0.f;
    #pragma unroll
    for (int c = 0; c < 16; ++c) {
      float4 wv = wp[c];
      float4 hv = hp[c];
      z0 = fmaf(hv.x, wv.x, z0);
      z1 = fmaf(hv.y, wv.y, z1);
      z2 = fmaf(hv.z, wv.z, z2);
      z3 = fmaf(hv.w, wv.w, z3);
    }
    float z = fmaxf((z0 + z1) + (z2 + z3), 0.f);
    float v = z * W2[j];
    v += __shfl_xor(v, 1);
    v += __shfl_xor(v, 2);
    v += __shfl_xor(v, 4);
    v += __shfl_xor(v, 8);
    v += __shfl_xor(v, 16);
    v += __shfl_xor(v, 32);
    if (l == 0) out[b] = sig_nat(v + clsb2[0]);
  }
}

extern "C" void kernel_launch(void* const* d_in, const int* in_sizes, int n_in,
                              void* d_out, int out_size, void* d_ws, size_t ws_size,
                              hipStream_t stream) {
  const int*   x    = (const int*)d_in[0];
  const float* emb  = (const float*)d_in[1];
  const float* Wih0 = (const float*)d_in[2];
  const float* Whh0 = (const float*)d_in[3];
  const float* bih0 = (const float*)d_in[4];
  const float* bhh0 = (const float*)d_in[5];
  const float* Wih1 = (const float*)d_in[6];
  const float* Whh1 = (const float*)d_in[7];
  const float* bih1 = (const float*)d_in[8];
  const float* bhh1 = (const float*)d_in[9];
  const float* W1   = (const float*)d_in[10];
  const float* b1   = (const float*)d_in[11];
  const float* W2   = (const float*)d_in[12];
  const float* b2   = (const float*)d_in[13];
  float* out = (float*)d_out;

  char* ws = (char*)d_ws;
  const size_t XW0_BYTES = (size_t)BATCH * SEQ * G4 * sizeof(u16);  // 67108864
  u16* xwP     = (u16*)ws;       ws += XW0_BYTES;
  u32* Wih0T2  = (u32*)ws;       ws += (size_t)50 * G4 * sizeof(u32);
  float* b0c   = (float*)ws;     ws += G4 * sizeof(float);
  float4* b1q  = (float4*)ws;    ws += (size_t)HID * sizeof(float4);
  u32* Whh0h   = (u32*)ws;       ws += (size_t)G4 * 32 * sizeof(u32);
  u32* Wih1h   = (u32*)ws;       ws += (size_t)G4 * 32 * sizeof(u32);
  u32* Whh1h   = (u32*)ws;       ws += (size_t)G4 * 32 * sizeof(u32);

  prep_kernel<<<1, 256, 0, stream>>>(Wih0, Whh0, Wih1, Whh1, bih0, bhh0, bih1, bhh1,
                                     Wih0T2, b0c, b1q, Whh0h, Wih1h, Whh1h);
  xw0_kernel<<<(BATCH * SEQ) / TOK, 256, 0, stream>>>(x, emb, Wih0T2, b0c, xwP);
  lstm_fused_kernel<<<BATCH, 256, 0, stream>>>(xwP, Whh0h, Wih1h, Whh1h, b1q,
                                               W1, b1, W2, b2, out);
}

// Round 18
// 768.881 us; speedup vs baseline: 1.0151x; 1.0151x over previous
//
#include <hip/hip_runtime.h>
#include <hip/hip_bf16.h>

#define EMB_D 100
#define HID 64
#define G4 256
#define BATCH 128
#define SEQ 1024
#define TOK 64
#define LOG2E 1.44269504f

typedef _Float16 half2v __attribute__((ext_vector_type(2)));
typedef unsigned short u16;
typedef unsigned int   u32;

__device__ __forceinline__ float rcpf(float x) { return __builtin_amdgcn_rcpf(x); }
__device__ __forceinline__ float ex2(float x) { return __builtin_amdgcn_exp2f(x); }
__device__ __forceinline__ float sig_pre(float xp) { return rcpf(1.0f + ex2(-xp)); }
__device__ __forceinline__ float tanh_pre(float xp) {
  float t = ex2(-2.0f * fabsf(xp));
  return copysignf((1.0f - t) * rcpf(1.0f + t), xp);
}
__device__ __forceinline__ float tanh_nat(float x) {
  float t = ex2(-2.885390082f * fabsf(x));
  return copysignf((1.0f - t) * rcpf(1.0f + t), x);
}
__device__ __forceinline__ float sig_nat(float x) { return rcpf(1.0f + ex2(-LOG2E * x)); }

__device__ __forceinline__ float dot2(u32 h, u32 w, float acc) {
  return __builtin_amdgcn_fdot2(__builtin_bit_cast(half2v, h),
                                __builtin_bit_cast(half2v, w), acc, false);
}
__device__ __forceinline__ u32 packh2(float lo, float hi) {
  u16 a = __builtin_bit_cast(u16, (_Float16)lo);
  u16 b = __builtin_bit_cast(u16, (_Float16)hi);
  return (u32)a | ((u32)b << 16);
}
#define QP_XOR1 0xB1
#define QP_XOR2 0x4E
#define QP_XOR3 0x1B
#define QPERM(x, ctrl)                                                        \
  __builtin_bit_cast(float, __builtin_amdgcn_mov_dpp(                         \
      __builtin_bit_cast(int, (x)), (ctrl), 0xF, 0xF, true))

// --- prep: biases + packed weights, pre-scaled by log2(e) (R16) ---
__global__ void prep_kernel(const float* __restrict__ Wih0,
                            const float* __restrict__ Whh0, const float* __restrict__ Wih1,
                            const float* __restrict__ Whh1,
                            const float* __restrict__ bih0, const float* __restrict__ bhh0,
                            const float* __restrict__ bih1, const float* __restrict__ bhh1,
                            u32* __restrict__ Wih0T2, float* __restrict__ b0c,
                            float* __restrict__ b1c,
                            u32* __restrict__ Whh0h, u32* __restrict__ Wih1h,
                            u32* __restrict__ Whh1h) {
  int g = threadIdx.x;
  b0c[g] = (bih0[g] + bhh0[g]) * LOG2E;
  b1c[g] = (bih1[g] + bhh1[g]) * LOG2E;
  for (int dp = 0; dp < 50; ++dp)
    Wih0T2[dp * G4 + g] = packh2(Wih0[g * EMB_D + 2 * dp] * LOG2E,
                                 Wih0[g * EMB_D + 2 * dp + 1] * LOG2E);
  for (int d = 0; d < 32; ++d) {
    Whh0h[g * 32 + d] = packh2(Whh0[g * HID + 2 * d] * LOG2E, Whh0[g * HID + 2 * d + 1] * LOG2E);
    Wih1h[g * 32 + d] = packh2(Wih1[g * HID + 2 * d] * LOG2E, Wih1[g * HID + 2 * d + 1] * LOG2E);
    Whh1h[g * 32 + d] = packh2(Whh1[g * HID + 2 * d] * LOG2E, Whh1[g * HID + 2 * d + 1] * LOG2E);
  }
}

// --- xw0: f16 dot2 GEMV, 64 tokens/block (R16) ---
__global__ __attribute__((amdgpu_waves_per_eu(1, 4))) __launch_bounds__(256)
void xw0_kernel(
    const int* __restrict__ x, const float* __restrict__ emb,
    const u32* __restrict__ Wih0T2, const float* __restrict__ b0c,
    _Float16* __restrict__ xw0h) {
  __shared__ int sidx[TOK];
  __shared__ alignas(16) u32 erow[TOK][52];
  int g = threadIdx.x;
  long t0 = (long)blockIdx.x * TOK;

  if (g < TOK) sidx[g] = x[t0 + g];
  __syncthreads();
  for (int i = g; i < TOK * 50; i += 256) {
    int tok = i / 50, dp = i - tok * 50;
    const float* er = emb + (size_t)sidx[tok] * EMB_D + 2 * dp;
    erow[tok][dp] = packh2(er[0], er[1]);
  }
  for (int i = g; i < TOK * 2; i += 256) erow[i >> 1][50 + (i & 1)] = 0;

  u32 wreg[52];
  #pragma unroll
  for (int dp = 0; dp < 50; ++dp) wreg[dp] = Wih0T2[dp * G4 + g];
  wreg[50] = 0; wreg[51] = 0;
  float bb = b0c[g];
  __syncthreads();

  for (int tok = 0; tok < TOK; ++tok) {
    const uint4* ep = (const uint4*)erow[tok];
    float a0 = bb, a1 = 0.f, a2 = 0.f, a3 = 0.f;
    #pragma unroll
    for (int c = 0; c < 13; ++c) {
      uint4 hv = ep[c];
      a0 = dot2(hv.x, wreg[4 * c],     a0);
      a1 = dot2(hv.y, wreg[4 * c + 1], a1);
      a2 = dot2(hv.z, wreg[4 * c + 2], a2);
      a3 = dot2(hv.w, wreg[4 * c + 3], a3);
    }
    xw0h[(t0 + tok) * G4 + g] = (_Float16)((a0 + a1) + (a2 + a3));
  }
}

// --- fused recurrence: wave-pair split, 2 waves/SIMD, 1 barrier/step ---
// 128 blocks x 512 threads (8 waves, 2/SIMD). Lane (e = (w&3)*16+(l>>2),
// k = l&3) owns row k*64+e. Waves 0-3 (lo): Whh0 row @ h0_{t-1} (32 dot2)
// -> h0_t; Wih1 row K-lo @ h0_{t-1} (16 dot2) -> ps. Waves 4-7 (hi, lag 2):
// Wih1 K-hi @ h0_{t-2} (16) + Whh1 row @ h1_{t-3} (32) + ps + bias -> h1_{t-2}.
// h0 triple-buffered; h1, ps double-buffered; ONE barrier/iter. Co-resident
// wave pair on each SIMD overlaps issue with the partner's latency stalls.
__global__ __attribute__((amdgpu_waves_per_eu(1, 2))) __launch_bounds__(512)
void lstm_fused_kernel(
    const _Float16* __restrict__ xw0h,
    const u32* __restrict__ Whh0h, const u32* __restrict__ Wih1h,
    const u32* __restrict__ Whh1h, const float* __restrict__ b1c,
    const float* __restrict__ W1, const float* __restrict__ clsb1,
    const float* __restrict__ W2, const float* __restrict__ clsb2,
    float* __restrict__ out) {
  int tid = threadIdx.x;
  int l = tid & 63;
  int w = tid >> 6;
  bool lo = (w < 4);
  int e = (w & 3) * 16 + (l >> 2);
  int k = l & 3;
  int row = k * HID + e;
  int b = blockIdx.x;

  __shared__ alignas(16) _Float16 h0s[3][HID];
  __shared__ alignas(16) _Float16 h1s[2][HID];
  __shared__ float ps[2][HID][4];       // [buf][e][k]: lane l -> bank l%32
  __shared__ alignas(16) float hf[HID];

  // weights: lo = Whh0 row (8 uint4) + Wih1 row K-lo (4); hi = Wih1 row K-hi
  // (4) + Whh1 row (8). 12 uint4 = 48 u32 per lane.
  uint4 wA[8], wP[4];
  if (lo) {
    const uint4* p = (const uint4*)(Whh0h + row * 32);
    #pragma unroll
    for (int c = 0; c < 8; ++c) wA[c] = p[c];
    const uint4* q = (const uint4*)(Wih1h + row * 32);
    #pragma unroll
    for (int c = 0; c < 4; ++c) wP[c] = q[c];
  } else {
    const uint4* q = (const uint4*)(Wih1h + row * 32);
    #pragma unroll
    for (int c = 0; c < 4; ++c) wP[c] = q[4 + c];
    const uint4* p = (const uint4*)(Whh1h + row * 32);
    #pragma unroll
    for (int c = 0; c < 8; ++c) wA[c] = p[c];
  }
  #pragma unroll
  for (int c = 0; c < 8; ++c)
    asm volatile("" : "+v"(wA[c].x), "+v"(wA[c].y), "+v"(wA[c].z), "+v"(wA[c].w));
  #pragma unroll
  for (int c = 0; c < 4; ++c)
    asm volatile("" : "+v"(wP[c].x), "+v"(wP[c].y), "+v"(wP[c].z), "+v"(wP[c].w));

  float bias = lo ? 0.f : b1c[row];

  if (tid < 3 * HID) ((u16*)h0s)[tid] = 0;
  else if (tid < 5 * HID) ((u16*)h1s)[tid - 3 * HID] = 0;

  const _Float16* xr = xw0h + (long)b * SEQ * G4 + row;
  float xw_t = 0.f, xw_t1 = 0.f;
  if (lo) { xw_t = (float)xr[0]; xw_t1 = (float)xr[G4]; }
  float c_reg = 0.f;
  __syncthreads();

  int rbLo = 2, rbHi = 1, wbH0 = 0;   // (t+2)%3, (t+1)%3, t%3
  for (int t = 0; t <= SEQ + 1; ++t) {
    if (lo) {
      if (t <= SEQ) {
        uint4 hc[8];
        const uint4* hp = (const uint4*)h0s[rbLo];   // h0_{t-1}
        #pragma unroll
        for (int c = 0; c < 8; ++c) hc[c] = hp[c];
        // Wih1 K-lo partial -> ps
        {
          float p0 = dot2(hc[0].x, wP[0].x, 0.f);
          float p1 = dot2(hc[0].y, wP[0].y, 0.f);
          float p2 = dot2(hc[0].z, wP[0].z, 0.f);
          float p3 = dot2(hc[0].w, wP[0].w, 0.f);
          #pragma unroll
          for (int c = 1; c < 4; ++c) {
            p0 = dot2(hc[c].x, wP[c].x, p0);
            p1 = dot2(hc[c].y, wP[c].y, p1);
            p2 = dot2(hc[c].z, wP[c].z, p2);
            p3 = dot2(hc[c].w, wP[c].w, p3);
          }
          ps[t & 1][e][k] = (p0 + p1) + (p2 + p3);
        }
        if (t < SEQ) {
          float a0 = xw_t, a1 = 0.f, a2 = 0.f, a3 = 0.f;
          #pragma unroll
          for (int c = 0; c < 8; ++c) {
            a0 = dot2(hc[c].x, wA[c].x, a0);
            a1 = dot2(hc[c].y, wA[c].y, a1);
            a2 = dot2(hc[c].z, wA[c].z, a2);
            a3 = dot2(hc[c].w, wA[c].w, a3);
          }
          float g0 = (a0 + a1) + (a2 + a3);
          float gx1 = QPERM(g0, QP_XOR1);
          float gx2 = QPERM(g0, QP_XOR2);
          float gx3 = QPERM(g0, QP_XOR3);
          c_reg = sig_pre(gx1) * c_reg + sig_pre(g0) * tanh_pre(gx2);
          float hv = sig_pre(gx3) * tanh_nat(c_reg);
          if (k == 0) h0s[wbH0][e] = (_Float16)hv;
          int tn = (t + 2 < SEQ) ? (t + 2) : (SEQ - 1);
          float xw_t2 = (float)xr[(long)tn * G4];
          xw_t = xw_t1; xw_t1 = xw_t2;
        }
      }
    } else {
      if (t >= 2) {
        const uint4* hp0 = (const uint4*)h0s[rbHi];          // h0_{t-2}
        const uint4* hp1 = (const uint4*)h1s[(t + 1) & 1];   // h1_{t-3}
        uint4 hh[4], h1c[8];
        #pragma unroll
        for (int c = 0; c < 4; ++c) hh[c] = hp0[4 + c];      // K-hi half
        #pragma unroll
        for (int c = 0; c < 8; ++c) h1c[c] = hp1[c];
        float psv = ps[(t + 1) & 1][e][k];
        float a0 = bias, a1 = 0.f, a2 = 0.f, a3 = 0.f;
        #pragma unroll
        for (int c = 0; c < 4; ++c) {
          a0 = dot2(hh[c].x, wP[c].x, a0);
          a1 = dot2(hh[c].y, wP[c].y, a1);
          a2 = dot2(hh[c].z, wP[c].z, a2);
          a3 = dot2(hh[c].w, wP[c].w, a3);
        }
        float b0 = dot2(h1c[0].x, wA[0].x, 0.f);
        float b1 = dot2(h1c[0].y, wA[0].y, 0.f);
        float b2 = dot2(h1c[0].z, wA[0].z, 0.f);
        float b3 = dot2(h1c[0].w, wA[0].w, 0.f);
        #pragma unroll
        for (int c = 1; c < 8; ++c) {
          b0 = dot2(h1c[c].x, wA[c].x, b0);
          b1 = dot2(h1c[c].y, wA[c].y, b1);
          b2 = dot2(h1c[c].z, wA[c].z, b2);
          b3 = dot2(h1c[c].w, wA[c].w, b3);
        }
        float g1 = (((a0 + a1) + (a2 + a3)) + ((b0 + b1) + (b2 + b3))) + psv;
        float gx1 = QPERM(g1, QP_XOR1);
        float gx2 = QPERM(g1, QP_XOR2);
        float gx3 = QPERM(g1, QP_XOR3);
        c_reg = sig_pre(gx1) * c_reg + sig_pre(g1) * tanh_pre(gx2);
        float hv = sig_pre(gx3) * tanh_nat(c_reg);
        if (k == 0) {
          h1s[t & 1][e] = (_Float16)hv;
          if (t == SEQ + 1) hf[e] = hv;
        }
      }
    }
    rbLo = (rbLo == 2) ? 0 : rbLo + 1;
    rbHi = (rbHi == 2) ? 0 : rbHi + 1;
    wbH0 = (wbH0 == 2) ? 0 : wbH0 + 1;
    asm volatile("s_waitcnt lgkmcnt(0)" ::: "memory");
    __builtin_amdgcn_s_barrier();
    asm volatile("" ::: "memory");
  }
  __syncthreads();

  // classifier (wave 0): z = relu(h1.W1^T + b1); out = sigmoid(z.W2 + b2)
  if (w == 0) {
    int j = l;
    const float4* wp = (const float4*)(W1 + j * HID);
    const float4* hp = (const float4*)hf;
    float z0 = clsb1[j], z1 = 0.f, z2 = 0.f, z3 = 0.f;
    #pragma unroll
    for (int c = 0; c < 16; ++c) {
      float4 wv = wp[c];
      float4 hv = hp[c];
      z0 = fmaf(hv.x, wv.x, z0);
      z1 = fmaf(hv.y, wv.y, z1);
      z2 = fmaf(hv.z, wv.z, z2);
      z3 = fmaf(hv.w, wv.w, z3);
    }
    float z = fmaxf((z0 + z1) + (z2 + z3), 0.f);
    float v = z * W2[j];
    v += __shfl_xor(v, 1);
    v += __shfl_xor(v, 2);
    v += __shfl_xor(v, 4);
    v += __shfl_xor(v, 8);
    v += __shfl_xor(v, 16);
    v += __shfl_xor(v, 32);
    if (l == 0) out[b] = sig_nat(v + clsb2[0]);
  }
}

extern "C" void kernel_launch(void* const* d_in, const int* in_sizes, int n_in,
                              void* d_out, int out_size, void* d_ws, size_t ws_size,
                              hipStream_t stream) {
  const int*   x    = (const int*)d_in[0];
  const float* emb  = (const float*)d_in[1];
  const float* Wih0 = (const float*)d_in[2];
  const float* Whh0 = (const float*)d_in[3];
  const float* bih0 = (const float*)d_in[4];
  const float* bhh0 = (const float*)d_in[5];
  const float* Wih1 = (const float*)d_in[6];
  const float* Whh1 = (const float*)d_in[7];
  const float* bih1 = (const float*)d_in[8];
  const float* bhh1 = (const float*)d_in[9];
  const float* W1   = (const float*)d_in[10];
  const float* b1   = (const float*)d_in[11];
  const float* W2   = (const float*)d_in[12];
  const float* b2   = (const float*)d_in[13];
  float* out = (float*)d_out;

  char* ws = (char*)d_ws;
  const size_t XW0_BYTES = (size_t)BATCH * SEQ * G4 * sizeof(_Float16);  // 67108864
  _Float16* xw0h = (_Float16*)ws;     ws += XW0_BYTES;
  u32* Wih0T2    = (u32*)ws;          ws += (size_t)50 * G4 * sizeof(u32);
  float* b0c     = (float*)ws;        ws += G4 * sizeof(float);
  float* b1c     = (float*)ws;        ws += G4 * sizeof(float);
  u32* Whh0h     = (u32*)ws;          ws += (size_t)G4 * 32 * sizeof(u32);
  u32* Wih1h     = (u32*)ws;          ws += (size_t)G4 * 32 * sizeof(u32);
  u32* Whh1h     = (u32*)ws;          ws += (size_t)G4 * 32 * sizeof(u32);

  prep_kernel<<<1, 256, 0, stream>>>(Wih0, Whh0, Wih1, Whh1, bih0, bhh0, bih1, bhh1,
                                     Wih0T2, b0c, b1c, Whh0h, Wih1h, Whh1h);
  xw0_kernel<<<(BATCH * SEQ) / TOK, 256, 0, stream>>>(x, emb, Wih0T2, b0c, xw0h);
  lstm_fused_kernel<<<BATCH, 512, 0, stream>>>(xw0h, Whh0h, Wih1h, Whh1h, b1c,
                                               W1, b1, W2, b2, out);
}